// Round 6
// baseline (2619.887 us; speedup 1.0000x reference)
//
#include <hip/hip_runtime.h>
#include <hip/hip_bf16.h>

#define TT    2048
#define BATCH 64
#define IDIM  128
#define HDIM  256
#define ODIM  512
#define M1    (BATCH * TT)   // 131072 rows

typedef __bf16 bf16x4 __attribute__((ext_vector_type(4)));
typedef __bf16 bf16x8 __attribute__((ext_vector_type(8)));
typedef float  f32x4  __attribute__((ext_vector_type(4)));
typedef float  f32x2  __attribute__((ext_vector_type(2)));
typedef _Float16 f16;
typedef _Float16 f16x4 __attribute__((ext_vector_type(4)));
typedef _Float16 f16x8 __attribute__((ext_vector_type(8)));

// ---------------------------------------------------------------------------
// GEMM (B-transposed weights): C[m][n] = sum_k A[m][k]*Bw[n][k] + bias[n]
// (unchanged — passes, ~145 us combined, not the bottleneck)
// ---------------------------------------------------------------------------
template<int BM, int NW, int N, int K>
__global__ __launch_bounds__(NW * 64)
void gemm_bt(const float* __restrict__ A, const float* __restrict__ Bw,
             const float* __restrict__ bias, float* __restrict__ C)
{
    constexpr int BN = NW * 64;
    constexpr int BK = 32;
    constexpr int PK = BK + 8;
    constexpr int MF = BM / 16;
    __shared__ __bf16 As[BM][PK];
    __shared__ __bf16 Bs[BN][PK];

    const int tid  = threadIdx.x;
    const int lane = tid & 63;
    const int wave = tid >> 6;
    const int l15  = lane & 15;
    const int l4   = lane >> 4;
    const long mrow = (long)blockIdx.x * BM;

    f32x4 acc[MF][4];
#pragma unroll
    for (int i = 0; i < MF; ++i)
#pragma unroll
        for (int j = 0; j < 4; ++j) acc[i][j] = (f32x4){0.f, 0.f, 0.f, 0.f};

    constexpr int THR   = NW * 64;
    constexpr int A_IT  = (BM * BK) / (THR * 4);
    constexpr int B_IT  = (BN * BK) / (THR * 4);

    for (int k0 = 0; k0 < K; k0 += BK) {
#pragma unroll
        for (int it = 0; it < A_IT; ++it) {
            int e = tid * 4 + it * THR * 4;
            int r = e / BK, c = e % BK;
            float4 v = *(const float4*)(A + (mrow + r) * K + (k0 + c));
            bf16x4 p = {(__bf16)v.x, (__bf16)v.y, (__bf16)v.z, (__bf16)v.w};
            *(bf16x4*)&As[r][c] = p;
        }
#pragma unroll
        for (int it = 0; it < B_IT; ++it) {
            int e = tid * 4 + it * THR * 4;
            int r = e / BK, c = e % BK;
            float4 v = *(const float4*)(Bw + (long)r * K + (k0 + c));
            bf16x4 p = {(__bf16)v.x, (__bf16)v.y, (__bf16)v.z, (__bf16)v.w};
            *(bf16x4*)&Bs[r][c] = p;
        }
        __syncthreads();

        const int kk = l4 * 8;
        bf16x8 a[MF], b[4];
#pragma unroll
        for (int mf = 0; mf < MF; ++mf)
            a[mf] = *(const bf16x8*)&As[mf * 16 + l15][kk];
#pragma unroll
        for (int nf = 0; nf < 4; ++nf)
            b[nf] = *(const bf16x8*)&Bs[wave * 64 + nf * 16 + l15][kk];
#pragma unroll
        for (int mf = 0; mf < MF; ++mf)
#pragma unroll
            for (int nf = 0; nf < 4; ++nf)
                acc[mf][nf] = __builtin_amdgcn_mfma_f32_16x16x32_bf16(
                    a[mf], b[nf], acc[mf][nf], 0, 0, 0);
        __syncthreads();
    }

#pragma unroll
    for (int nf = 0; nf < 4; ++nf) {
        const int col = wave * 64 + nf * 16 + l15;
        const float bv = bias[col];
#pragma unroll
        for (int mf = 0; mf < MF; ++mf) {
#pragma unroll
            for (int j = 0; j < 4; ++j) {
                long row = mrow + mf * 16 + l4 * 4 + j;
                C[row * N + col] = acc[mf][nf][j] + bv;
            }
        }
    }
}

// ---------------------------------------------------------------------------
// MFMA scan: 4 blocks x 16 batches. pre^T[g][batch] = Whh * h^T per step.
//   256 threads = 4 waves; wave owns g-range [64w, 64w+64) (4 M-tiles).
//   A = Whh static in registers: Wf[mt][kt], lane holds
//     Whh[64w+16mt+(l&15)][32kt+8(l>>4)+0..7]  (verified gemm A-frag layout).
//   B = h from LDS row-major [16 batch][264 pad] f16, double-buffered:
//     lane reads hs[l&15][32kt+8(l>>4)] as f16x8 (verified B-frag layout).
//   C: lane holds pre[g=64w+16mt+4(l>>4)+j][batch=l&15] (verified C layout)
//     -> h-write is 4 CONSECUTIVE g per lane: one ds_write_b64. No transpose.
//   h_old kept f32 in registers at C positions; tanh epilogue per output;
//   raw s_barrier with lgkmcnt-only drain; xp prefetch ~2 steps deep.
// ---------------------------------------------------------------------------
#define ROWP 264   // padded LDS row stride in f16 (264*2B=528B -> 2-way banks)

__global__ __launch_bounds__(256, 1)
void rnn_scan_mfma(const float* __restrict__ xp, const float* __restrict__ h0,
                   const float* __restrict__ Whh, float* __restrict__ h_all)
{
    __shared__ f16 hs[2][16 * ROWP];
    const int tid  = threadIdx.x;
    const int w    = tid >> 6;
    const int lane = tid & 63;
    const int q    = lane >> 4;          // 0..3
    const int c    = lane & 15;          // 0..15 (= batch column / A row)
    const int bi   = blockIdx.x;
    const int batch = bi * 16 + c;

    // ---- static A-fragments (f32 -> f16 once)
    f16x8 Wf[4][8];
#pragma unroll
    for (int mt = 0; mt < 4; ++mt) {
        const float* wr = Whh + (long)(w * 64 + mt * 16 + c) * HDIM + q * 8;
#pragma unroll
        for (int kt = 0; kt < 8; ++kt) {
            f32x4 u0 = *(const f32x4*)(wr + kt * 32);
            f32x4 u1 = *(const f32x4*)(wr + kt * 32 + 4);
            Wf[mt][kt] = (f16x8){(f16)u0[0], (f16)u0[1], (f16)u0[2], (f16)u0[3],
                                 (f16)u1[0], (f16)u1[1], (f16)u1[2], (f16)u1[3]};
        }
    }

    // ---- init LDS h buffer 0 (f16) : row r = batch bi*16+r
    {
        const int r  = tid >> 4;         // 0..15
        const int cc = tid & 15;         // 16-float chunk
        const float* hr = h0 + (long)(bi * 16 + r) * HDIM + cc * 16;
        f16 tmp[16];
#pragma unroll
        for (int i = 0; i < 16; i += 4) {
            f32x4 u = *(const f32x4*)(hr + i);
            tmp[i] = (f16)u[0]; tmp[i+1] = (f16)u[1];
            tmp[i+2] = (f16)u[2]; tmp[i+3] = (f16)u[3];
        }
        *(f16x8*)&hs[0][r * ROWP + cc * 16]     = *(const f16x8*)&tmp[0];
        *(f16x8*)&hs[0][r * ROWP + cc * 16 + 8] = *(const f16x8*)&tmp[8];
    }

    // ---- h_old registers at C positions: hold[mt][j] = h0[batch][64w+16mt+4q+j]
    f32x4 hold[4];
#pragma unroll
    for (int mt = 0; mt < 4; ++mt)
        hold[mt] = *(const f32x4*)(h0 + (long)batch * HDIM + w * 64 + mt * 16 + q * 4);
    __syncthreads();

    const long g0   = w * 64 + q * 4;                 // + 16*mt
    const float* xpb = xp    + (long)batch * TT * HDIM + g0;
    float*       hab = h_all + (long)batch * TT * HDIM + g0;

    // xp prefetch: xq0 = t data, xq1 = t+1 data
    f32x4 xq0[4], xq1[4];
#pragma unroll
    for (int mt = 0; mt < 4; ++mt) xq0[mt] = *(const f32x4*)(xpb + mt * 16);
#pragma unroll
    for (int mt = 0; mt < 4; ++mt) xq1[mt] = *(const f32x4*)(xpb + HDIM + mt * 16);

    const int rdbase = c * ROWP + q * 8;              // f16 idx; + 32*kt
    const int wrIdx  = c * ROWP + w * 64 + q * 4;     // f16 idx; + 16*mt

    for (int t = 0; t < TT; ++t) {
        const f16* hb = hs[t & 1];
        f16x8 Bf[8];
#pragma unroll
        for (int kt = 0; kt < 8; ++kt)
            Bf[kt] = *(const f16x8*)(hb + rdbase + kt * 32);

        f32x4 acc[4];
#pragma unroll
        for (int mt = 0; mt < 4; ++mt) acc[mt] = (f32x4){0.f, 0.f, 0.f, 0.f};
#pragma unroll
        for (int kt = 0; kt < 8; ++kt)
#pragma unroll
            for (int mt = 0; mt < 4; ++mt)
                acc[mt] = __builtin_amdgcn_mfma_f32_16x16x32_f16(
                    Wf[mt][kt], Bf[kt], acc[mt], 0, 0, 0);

        f16* hw = &hs[(t + 1) & 1][0];
        const long tn = (long)((t + 2 < TT) ? (t + 2) : (TT - 1)) * HDIM;

#pragma unroll
        for (int mt = 0; mt < 4; ++mt) {
            f32x4 hn;
#pragma unroll
            for (int j = 0; j < 4; ++j) {
                float pre = acc[mt][j] + xq0[mt][j];
                float e   = __expf(2.f * pre);
                float r   = __builtin_amdgcn_rcpf(1.f + e);
                hn[j] = fmaf(0.9f, hold[mt][j], 0.1f) - 0.2f * r;
            }
            hold[mt] = hn;
            f16x4 hp = {(f16)hn[0], (f16)hn[1], (f16)hn[2], (f16)hn[3]};
            *(f16x4*)&hw[wrIdx + 16 * mt] = hp;                  // ds_write_b64
            *(f32x4*)(hab + (long)t * HDIM + mt * 16) = hn;      // global, in flight
            xq0[mt] = xq1[mt];
            xq1[mt] = *(const f32x4*)(xpb + tn + mt * 16);       // prefetch t+2
        }

        // ---- raw barrier: LDS visibility only, NO vmcnt drain ----
        __builtin_amdgcn_sched_barrier(0);
        asm volatile("s_waitcnt lgkmcnt(0)" ::: "memory");
        __builtin_amdgcn_s_barrier();
        __builtin_amdgcn_sched_barrier(0);
    }
}

// ---------------------------------------------------------------------------
extern "C" void kernel_launch(void* const* d_in, const int* in_sizes, int n_in,
                              void* d_out, int out_size, void* d_ws, size_t ws_size,
                              hipStream_t stream)
{
    const float* x   = (const float*)d_in[0];
    const float* h0  = (const float*)d_in[1];
    const float* Wxh = (const float*)d_in[2];
    const float* bxh = (const float*)d_in[3];
    const float* Whh = (const float*)d_in[4];
    const float* Why = (const float*)d_in[5];
    const float* bhy = (const float*)d_in[6];

    float* y     = (float*)d_out;                 // (M1, 512)
    float* h_all = y + (long)M1 * ODIM;           // (M1, 256)
    float* xp    = y;   // scratch: xp fits in y region; dead before K3

    gemm_bt<64, 4, HDIM, IDIM><<<M1 / 64, 4 * 64, 0, stream>>>(x, Wxh, bxh, xp);
    rnn_scan_mfma<<<4, 256, 0, stream>>>(xp, h0, Whh, h_all);
    gemm_bt<64, 8, ODIM, HDIM><<<M1 / 64, 8 * 64, 0, stream>>>(h_all, Why, bhy, y);
}

// Round 7
// 1492.916 us; speedup vs baseline: 1.7549x; 1.7549x over previous
//
#include <hip/hip_runtime.h>
#include <hip/hip_bf16.h>

#define TT    2048
#define BATCH 64
#define IDIM  128
#define HDIM  256
#define ODIM  512
#define M1    (BATCH * TT)   // 131072 rows

typedef __bf16 bf16x4 __attribute__((ext_vector_type(4)));
typedef __bf16 bf16x8 __attribute__((ext_vector_type(8)));
typedef float  f32x4  __attribute__((ext_vector_type(4)));
typedef _Float16 f16;
typedef _Float16 f16x4 __attribute__((ext_vector_type(4)));
typedef _Float16 f16x8 __attribute__((ext_vector_type(8)));

// ---------------------------------------------------------------------------
// GEMM (B-transposed weights): C[m][n] = sum_k A[m][k]*Bw[n][k] + bias[n]
// (unchanged — passes, not the bottleneck)
// ---------------------------------------------------------------------------
template<int BM, int NW, int N, int K>
__global__ __launch_bounds__(NW * 64)
void gemm_bt(const float* __restrict__ A, const float* __restrict__ Bw,
             const float* __restrict__ bias, float* __restrict__ C)
{
    constexpr int BN = NW * 64;
    constexpr int BK = 32;
    constexpr int PK = BK + 8;
    constexpr int MF = BM / 16;
    __shared__ __bf16 As[BM][PK];
    __shared__ __bf16 Bs[BN][PK];

    const int tid  = threadIdx.x;
    const int lane = tid & 63;
    const int wave = tid >> 6;
    const int l15  = lane & 15;
    const int l4   = lane >> 4;
    const long mrow = (long)blockIdx.x * BM;

    f32x4 acc[MF][4];
#pragma unroll
    for (int i = 0; i < MF; ++i)
#pragma unroll
        for (int j = 0; j < 4; ++j) acc[i][j] = (f32x4){0.f, 0.f, 0.f, 0.f};

    constexpr int THR   = NW * 64;
    constexpr int A_IT  = (BM * BK) / (THR * 4);
    constexpr int B_IT  = (BN * BK) / (THR * 4);

    for (int k0 = 0; k0 < K; k0 += BK) {
#pragma unroll
        for (int it = 0; it < A_IT; ++it) {
            int e = tid * 4 + it * THR * 4;
            int r = e / BK, c = e % BK;
            float4 v = *(const float4*)(A + (mrow + r) * K + (k0 + c));
            bf16x4 p = {(__bf16)v.x, (__bf16)v.y, (__bf16)v.z, (__bf16)v.w};
            *(bf16x4*)&As[r][c] = p;
        }
#pragma unroll
        for (int it = 0; it < B_IT; ++it) {
            int e = tid * 4 + it * THR * 4;
            int r = e / BK, c = e % BK;
            float4 v = *(const float4*)(Bw + (long)r * K + (k0 + c));
            bf16x4 p = {(__bf16)v.x, (__bf16)v.y, (__bf16)v.z, (__bf16)v.w};
            *(bf16x4*)&Bs[r][c] = p;
        }
        __syncthreads();

        const int kk = l4 * 8;
        bf16x8 a[MF], b[4];
#pragma unroll
        for (int mf = 0; mf < MF; ++mf)
            a[mf] = *(const bf16x8*)&As[mf * 16 + l15][kk];
#pragma unroll
        for (int nf = 0; nf < 4; ++nf)
            b[nf] = *(const bf16x8*)&Bs[wave * 64 + nf * 16 + l15][kk];
#pragma unroll
        for (int mf = 0; mf < MF; ++mf)
#pragma unroll
            for (int nf = 0; nf < 4; ++nf)
                acc[mf][nf] = __builtin_amdgcn_mfma_f32_16x16x32_bf16(
                    a[mf], b[nf], acc[mf][nf], 0, 0, 0);
        __syncthreads();
    }

#pragma unroll
    for (int nf = 0; nf < 4; ++nf) {
        const int col = wave * 64 + nf * 16 + l15;
        const float bv = bias[col];
#pragma unroll
        for (int mf = 0; mf < MF; ++mf) {
#pragma unroll
            for (int j = 0; j < 4; ++j) {
                long row = mrow + mf * 16 + l4 * 4 + j;
                C[row * N + col] = acc[mf][nf][j] + bv;
            }
        }
    }
}

// ---------------------------------------------------------------------------
// MFMA scan, 1 batch/block x 64 blocks (fixes R6's 4-CU VMEM saturation).
//   512 threads = 8 waves; wave w owns g-rows [32w, 32w+32) = 2 M-tiles.
//   A = Whh rows in registers (verified A-frag layout: row=16mt+c, k=8q+j).
//   B = h BROADCAST into all 16 MFMA columns: every column computes the
//       same pre vector. B-frag read is c-independent (hs + 32kt + 8q),
//       a wave-broadcast ds_read_b128 — free, no conflicts.
//   C: lane (q,c) holds pre[32w+16mt+4q+j] duplicated across c.
//   Epilogue de-dup: lane finalizes mt=c&1 (tanh x4); lanes c<2 write
//   h'->LDS (f16x4) and h_all->global (f32x4, stays in flight).
//   Raw s_barrier with lgkmcnt-only drain; xp prefetch depth 2.
// ---------------------------------------------------------------------------
__global__ __launch_bounds__(512, 1)
void rnn_scan_mfma(const float* __restrict__ xp, const float* __restrict__ h0,
                   const float* __restrict__ Whh, float* __restrict__ h_all)
{
    __shared__ f16 hs[2][HDIM];
    const int tid  = threadIdx.x;
    const int w    = tid >> 6;           // wave 0..7
    const int lane = tid & 63;
    const int q    = lane >> 4;          // 0..3
    const int c    = lane & 15;          // 0..15 (MFMA column / A-row-in-tile)
    const int b    = blockIdx.x;         // batch

    // ---- static A-fragments: Wf[mt][kt] = Whh[32w+16mt+c][32kt+8q+0..7]
    f16x8 Wf[2][8];
#pragma unroll
    for (int mt = 0; mt < 2; ++mt) {
        const float* wr = Whh + (long)(32 * w + 16 * mt + c) * HDIM + 8 * q;
#pragma unroll
        for (int kt = 0; kt < 8; ++kt) {
            f32x4 u0 = *(const f32x4*)(wr + 32 * kt);
            f32x4 u1 = *(const f32x4*)(wr + 32 * kt + 4);
            Wf[mt][kt] = (f16x8){(f16)u0[0], (f16)u0[1], (f16)u0[2], (f16)u0[3],
                                 (f16)u1[0], (f16)u1[1], (f16)u1[2], (f16)u1[3]};
        }
    }

    // ---- init h buffer 0 (f16)
    if (tid < HDIM) hs[0][tid] = (f16)h0[(long)b * HDIM + tid];

    // ---- per-lane finalized rows: g = 32w + 16*(c&1) + 4q + j, j=0..3
    const int mtf = c & 1;
    const int gb  = 32 * w + 16 * mtf + 4 * q;
    const bool wr_en = (c >> 1) == 0;    // c<2: one writer per (w,mtf,q)

    f32x4 hold = *(const f32x4*)(h0 + (long)b * HDIM + gb);
    __syncthreads();

    const float* xpb = xp    + (long)b * TT * HDIM + gb;
    float*       hab = h_all + (long)b * TT * HDIM + gb;

    f32x4 xq0 = *(const f32x4*)(xpb);
    f32x4 xq1 = *(const f32x4*)(xpb + HDIM);

    for (int t = 0; t < TT; ++t) {
        const f16* hb = hs[t & 1];
        f16x8 Bf[8];
#pragma unroll
        for (int kt = 0; kt < 8; ++kt)
            Bf[kt] = *(const f16x8*)(hb + 32 * kt + 8 * q);   // wave-broadcast

        // prefetch xp for t+2 (stays in flight across the raw barrier)
        const long tn = (long)((t + 2 < TT) ? (t + 2) : (TT - 1)) * HDIM;
        f32x4 xq2 = *(const f32x4*)(xpb + tn);

        f32x4 acc0 = (f32x4){0.f, 0.f, 0.f, 0.f};
        f32x4 acc1 = (f32x4){0.f, 0.f, 0.f, 0.f};
#pragma unroll
        for (int kt = 0; kt < 8; ++kt) {
            acc0 = __builtin_amdgcn_mfma_f32_16x16x32_f16(Wf[0][kt], Bf[kt], acc0, 0, 0, 0);
            acc1 = __builtin_amdgcn_mfma_f32_16x16x32_f16(Wf[1][kt], Bf[kt], acc1, 0, 0, 0);
        }
        f32x4 accs;
#pragma unroll
        for (int j = 0; j < 4; ++j) accs[j] = mtf ? acc1[j] : acc0[j];

        // ---- epilogue: 4 outputs per lane (8-fold dup across c>>1)
        f32x4 hn;
#pragma unroll
        for (int j = 0; j < 4; ++j) {
            float pre = accs[j] + xq0[j];
            float e   = __expf(2.f * pre);
            float r   = __builtin_amdgcn_rcpf(1.f + e);
            // 0.9*h + 0.1*tanh = 0.9*h + 0.1 - 0.2/(1+e^{2pre})
            hn[j] = fmaf(0.9f, hold[j], 0.1f) - 0.2f * r;
        }
        hold = hn;

        if (wr_en) {
            f16x4 hp = {(f16)hn[0], (f16)hn[1], (f16)hn[2], (f16)hn[3]};
            *(f16x4*)&hs[(t + 1) & 1][gb] = hp;       // ds_write_b64
            *(f32x4*)(hab) = hn;                      // global, stays in flight
        }
        hab += HDIM;
        xq0 = xq1; xq1 = xq2;

        // ---- raw barrier: LDS visibility only, NO vmcnt drain ----
        __builtin_amdgcn_sched_barrier(0);
        asm volatile("s_waitcnt lgkmcnt(0)" ::: "memory");
        __builtin_amdgcn_s_barrier();
        __builtin_amdgcn_sched_barrier(0);
    }
}

// ---------------------------------------------------------------------------
extern "C" void kernel_launch(void* const* d_in, const int* in_sizes, int n_in,
                              void* d_out, int out_size, void* d_ws, size_t ws_size,
                              hipStream_t stream)
{
    const float* x   = (const float*)d_in[0];
    const float* h0  = (const float*)d_in[1];
    const float* Wxh = (const float*)d_in[2];
    const float* bxh = (const float*)d_in[3];
    const float* Whh = (const float*)d_in[4];
    const float* Why = (const float*)d_in[5];
    const float* bhy = (const float*)d_in[6];

    float* y     = (float*)d_out;                 // (M1, 512)
    float* h_all = y + (long)M1 * ODIM;           // (M1, 256)
    float* xp    = y;   // scratch: xp fits in y region; dead before K3

    gemm_bt<64, 4, HDIM, IDIM><<<M1 / 64, 4 * 64, 0, stream>>>(x, Wxh, bxh, xp);
    rnn_scan_mfma<<<BATCH, 512, 0, stream>>>(xp, h0, Whh, h_all);
    gemm_bt<64, 8, ODIM, HDIM><<<M1 / 64, 8 * 64, 0, stream>>>(h_all, Why, bhy, y);
}

// Round 8
// 1181.269 us; speedup vs baseline: 2.2179x; 1.2638x over previous
//
#include <hip/hip_runtime.h>
#include <hip/hip_bf16.h>

#define TT    2048
#define BATCH 64
#define IDIM  128
#define HDIM  256
#define ODIM  512
#define M1    (BATCH * TT)   // 131072 rows

typedef __bf16 bf16x4 __attribute__((ext_vector_type(4)));
typedef __bf16 bf16x8 __attribute__((ext_vector_type(8)));
typedef float  f32x4  __attribute__((ext_vector_type(4)));
typedef _Float16 f16;
typedef _Float16 f16x8 __attribute__((ext_vector_type(8)));

// ---------------------------------------------------------------------------
// GEMM (B-transposed weights): C[m][n] = sum_k A[m][k]*Bw[n][k] + bias[n]
// (unchanged — passes, not the bottleneck)
// ---------------------------------------------------------------------------
template<int BM, int NW, int N, int K>
__global__ __launch_bounds__(NW * 64)
void gemm_bt(const float* __restrict__ A, const float* __restrict__ Bw,
             const float* __restrict__ bias, float* __restrict__ C)
{
    constexpr int BN = NW * 64;
    constexpr int BK = 32;
    constexpr int PK = BK + 8;
    constexpr int MF = BM / 16;
    __shared__ __bf16 As[BM][PK];
    __shared__ __bf16 Bs[BN][PK];

    const int tid  = threadIdx.x;
    const int lane = tid & 63;
    const int wave = tid >> 6;
    const int l15  = lane & 15;
    const int l4   = lane >> 4;
    const long mrow = (long)blockIdx.x * BM;

    f32x4 acc[MF][4];
#pragma unroll
    for (int i = 0; i < MF; ++i)
#pragma unroll
        for (int j = 0; j < 4; ++j) acc[i][j] = (f32x4){0.f, 0.f, 0.f, 0.f};

    constexpr int THR   = NW * 64;
    constexpr int A_IT  = (BM * BK) / (THR * 4);
    constexpr int B_IT  = (BN * BK) / (THR * 4);

    for (int k0 = 0; k0 < K; k0 += BK) {
#pragma unroll
        for (int it = 0; it < A_IT; ++it) {
            int e = tid * 4 + it * THR * 4;
            int r = e / BK, c = e % BK;
            float4 v = *(const float4*)(A + (mrow + r) * K + (k0 + c));
            bf16x4 p = {(__bf16)v.x, (__bf16)v.y, (__bf16)v.z, (__bf16)v.w};
            *(bf16x4*)&As[r][c] = p;
        }
#pragma unroll
        for (int it = 0; it < B_IT; ++it) {
            int e = tid * 4 + it * THR * 4;
            int r = e / BK, c = e % BK;
            float4 v = *(const float4*)(Bw + (long)r * K + (k0 + c));
            bf16x4 p = {(__bf16)v.x, (__bf16)v.y, (__bf16)v.z, (__bf16)v.w};
            *(bf16x4*)&Bs[r][c] = p;
        }
        __syncthreads();

        const int kk = l4 * 8;
        bf16x8 a[MF], b[4];
#pragma unroll
        for (int mf = 0; mf < MF; ++mf)
            a[mf] = *(const bf16x8*)&As[mf * 16 + l15][kk];
#pragma unroll
        for (int nf = 0; nf < 4; ++nf)
            b[nf] = *(const bf16x8*)&Bs[wave * 64 + nf * 16 + l15][kk];
#pragma unroll
        for (int mf = 0; mf < MF; ++mf)
#pragma unroll
            for (int nf = 0; nf < 4; ++nf)
                acc[mf][nf] = __builtin_amdgcn_mfma_f32_16x16x32_bf16(
                    a[mf], b[nf], acc[mf][nf], 0, 0, 0);
        __syncthreads();
    }

#pragma unroll
    for (int nf = 0; nf < 4; ++nf) {
        const int col = wave * 64 + nf * 16 + l15;
        const float bv = bias[col];
#pragma unroll
        for (int mf = 0; mf < MF; ++mf) {
#pragma unroll
            for (int j = 0; j < 4; ++j) {
                long row = mrow + mf * 16 + l4 * 4 + j;
                C[row * N + col] = acc[mf][nf][j] + bv;
            }
        }
    }
}

// ---------------------------------------------------------------------------
// MFMA scan, 1 batch/block x 64 blocks, deduped epilogue + split chains.
//   512 threads = 8 waves; wave w owns g-rows [32w, 32w+32) = 2 M-tiles.
//   A = Whh rows in registers (A-frag: row=16mt+c, k=8q+j — verified).
//   B = h broadcast to all 16 MFMA columns (c-independent ds_read_b128).
//   MFMA: 4 independent chains of 4 (kt 0-3 / 4-7 per mt) + packed combine.
//   Epilogue: lane bits c={mt,j,j,dup} -> ONE row r=32w+16mt+4q+j per lane,
//   ONE tanh; dup==0 lanes write h'->LDS (b16) and h_all->global (b32,
//   32 lanes = contiguous 128B per wave). xp: 1 scalar/lane, prefetch x2.
//   Raw s_barrier with lgkmcnt-only drain (globals stay in flight).
// ---------------------------------------------------------------------------
__global__ __launch_bounds__(512, 1)
void rnn_scan_mfma(const float* __restrict__ xp, const float* __restrict__ h0,
                   const float* __restrict__ Whh, float* __restrict__ h_all)
{
    __shared__ f16 hs[2][HDIM];
    const int tid  = threadIdx.x;
    const int w    = tid >> 6;           // wave 0..7
    const int lane = tid & 63;
    const int q    = lane >> 4;          // 0..3
    const int c    = lane & 15;          // 0..15 (MFMA column)
    const int b    = blockIdx.x;         // batch

    const int mt  = c & 1;               // which m-tile this lane finalizes
    const int jj  = (c >> 1) & 3;        // which acc component
    const bool wr_en = (c >> 3) == 0;    // dup==0 -> writer
    const int r   = 32 * w + 16 * mt + 4 * q + jj;   // this lane's row

    // ---- static A-fragments: Wf[m][kt] = Whh[32w+16m+c][32kt+8q+0..7]
    f16x8 Wf[2][8];
#pragma unroll
    for (int m = 0; m < 2; ++m) {
        const float* wrp = Whh + (long)(32 * w + 16 * m + c) * HDIM + 8 * q;
#pragma unroll
        for (int kt = 0; kt < 8; ++kt) {
            f32x4 u0 = *(const f32x4*)(wrp + 32 * kt);
            f32x4 u1 = *(const f32x4*)(wrp + 32 * kt + 4);
            Wf[m][kt] = (f16x8){(f16)u0[0], (f16)u0[1], (f16)u0[2], (f16)u0[3],
                                (f16)u1[0], (f16)u1[1], (f16)u1[2], (f16)u1[3]};
        }
    }

    // ---- init h buffer 0 (f16) + per-lane h register for row r
    if (tid < HDIM) hs[0][tid] = (f16)h0[(long)b * HDIM + tid];
    float hold = h0[(long)b * HDIM + r];
    __syncthreads();

    const float* xpb = xp    + (long)b * TT * HDIM + r;
    float*       hab = h_all + (long)b * TT * HDIM + r;

    float xq0 = xpb[0];
    float xq1 = xpb[HDIM];

    for (int t = 0; t < TT; ++t) {
        const f16* hb = hs[t & 1];
        f16x8 Bf[8];
#pragma unroll
        for (int kt = 0; kt < 8; ++kt)
            Bf[kt] = *(const f16x8*)(hb + 32 * kt + 8 * q);   // wave-broadcast

        // prefetch xp for t+2 (stays in flight across the raw barrier)
        const long tn = (long)((t + 2 < TT) ? (t + 2) : (TT - 1)) * HDIM;
        float xq2 = xpb[tn];

        // ---- 4 independent 4-deep MFMA chains ----
        f32x4 a0a = (f32x4){0.f,0.f,0.f,0.f}, a0b = (f32x4){0.f,0.f,0.f,0.f};
        f32x4 a1a = (f32x4){0.f,0.f,0.f,0.f}, a1b = (f32x4){0.f,0.f,0.f,0.f};
#pragma unroll
        for (int kt = 0; kt < 4; ++kt) {
            a0a = __builtin_amdgcn_mfma_f32_16x16x32_f16(Wf[0][kt],     Bf[kt],     a0a, 0, 0, 0);
            a1a = __builtin_amdgcn_mfma_f32_16x16x32_f16(Wf[1][kt],     Bf[kt],     a1a, 0, 0, 0);
            a0b = __builtin_amdgcn_mfma_f32_16x16x32_f16(Wf[0][kt + 4], Bf[kt + 4], a0b, 0, 0, 0);
            a1b = __builtin_amdgcn_mfma_f32_16x16x32_f16(Wf[1][kt + 4], Bf[kt + 4], a1b, 0, 0, 0);
        }
        f32x4 acc0 = a0a + a0b;
        f32x4 acc1 = a1a + a1b;

        // ---- lane-constant selection: acc[mt][jj] (cndmask chain, no scratch)
        float sx = (jj & 2) ? (mt ? acc1[2] : acc0[2]) : (mt ? acc1[0] : acc0[0]);
        float sy = (jj & 2) ? (mt ? acc1[3] : acc0[3]) : (mt ? acc1[1] : acc0[1]);
        float s  = (jj & 1) ? sy : sx;

        // ---- ONE tanh per lane ----
        float pre = s + xq0;
        float e   = __expf(2.f * pre);
        float rc  = __builtin_amdgcn_rcpf(1.f + e);
        float hn  = fmaf(0.9f, hold, 0.1f) - 0.2f * rc;   // 0.9h + 0.1*tanh
        hold = hn;

        if (wr_en) {
            hs[(t + 1) & 1][r] = (f16)hn;    // ds_write_b16
            hab[0] = hn;                     // global b32, stays in flight
        }
        hab += HDIM;
        xq0 = xq1; xq1 = xq2;

        // ---- raw barrier: LDS visibility only, NO vmcnt drain ----
        __builtin_amdgcn_sched_barrier(0);
        asm volatile("s_waitcnt lgkmcnt(0)" ::: "memory");
        __builtin_amdgcn_s_barrier();
        __builtin_amdgcn_sched_barrier(0);
    }
}

// ---------------------------------------------------------------------------
extern "C" void kernel_launch(void* const* d_in, const int* in_sizes, int n_in,
                              void* d_out, int out_size, void* d_ws, size_t ws_size,
                              hipStream_t stream)
{
    const float* x   = (const float*)d_in[0];
    const float* h0  = (const float*)d_in[1];
    const float* Wxh = (const float*)d_in[2];
    const float* bxh = (const float*)d_in[3];
    const float* Whh = (const float*)d_in[4];
    const float* Why = (const float*)d_in[5];
    const float* bhy = (const float*)d_in[6];

    float* y     = (float*)d_out;                 // (M1, 512)
    float* h_all = y + (long)M1 * ODIM;           // (M1, 256)
    float* xp    = y;   // scratch: xp fits in y region; dead before K3

    gemm_bt<64, 4, HDIM, IDIM><<<M1 / 64, 4 * 64, 0, stream>>>(x, Wxh, bxh, xp);
    rnn_scan_mfma<<<BATCH, 512, 0, stream>>>(xp, h0, Whh, h_all);
    gemm_bt<64, 8, ODIM, HDIM><<<M1 / 64, 8 * 64, 0, stream>>>(h_all, Why, bhy, y);
}